// Round 6
// baseline (422.284 us; speedup 1.0000x reference)
//
#include <hip/hip_runtime.h>
#include <stdint.h>

// W8A8B32O32 Linear: y[m][n] = sum_k x[m][k]*w[n][k] + bias[n]
// M=8192, N=4096, K=4096. Inputs arrive as int32 (one int per logical int8
// element); pack to int8 in d_ws, then run the i8 MFMA GEMM.
#define M_TOT 8192
#define N_TOT 4096
#define K_TOT 4096

typedef int v4i  __attribute__((ext_vector_type(4)));
typedef int v16i __attribute__((ext_vector_type(16)));

__device__ __forceinline__ void gload_lds16(const void* g, void* l) {
    __builtin_amdgcn_global_load_lds(
        (const __attribute__((address_space(1))) unsigned int*)g,
        (__attribute__((address_space(3))) unsigned int*)l,
        16, 0, 0);
}

// gfx9 s_waitcnt simm16: vmcnt[3:0]@[3:0], expcnt@[6:4], lgkmcnt@[11:8],
// vmcnt[5:4]@[15:14].
#define WAIT_V2_L0() __builtin_amdgcn_s_waitcnt(0x0072)  // vmcnt(2) lgkmcnt(0)
#define WAIT_V0_L0() __builtin_amdgcn_s_waitcnt(0x0070)  // vmcnt(0) lgkmcnt(0)
#define WAIT_V4()    __builtin_amdgcn_s_waitcnt(0x0f74)  // vmcnt(4), lgkm free
#define SBAR()       __builtin_amdgcn_s_barrier()
#define SFENCE()     __builtin_amdgcn_sched_barrier(0)

// ---- fused pack int32 -> int8: 64B loads -> 16B store per thread-iter ----
// BW-bound at 240 MB (~45 us); split and fused variants measure the same ->
// already at the traffic floor.
__global__ __launch_bounds__(256) void pack2(
        const int4* __restrict__ xs, int4* __restrict__ xd,
        const int4* __restrict__ ws, int4* __restrict__ wd) {
    const int t = blockIdx.x * 256 + threadIdx.x;       // 0..524287
#pragma unroll
    for (int it = 0; it < 6; ++it) {
        const long g = (long)it * 524288 + t;
        const int4* __restrict__ src = (it < 4) ? xs : ws;
        int4* __restrict__ dst       = (it < 4) ? xd : wd;
        const long o = (it < 4) ? g : g - 2097152;
        int4 r;
        int* rp = (int*)&r;
#pragma unroll
        for (int q = 0; q < 4; ++q) {
            const int4 a = src[o * 4 + q];
            rp[q] = (a.x & 255) | ((a.y & 255) << 8) |
                    ((a.z & 255) << 16) | (a.w << 24);
        }
        dst[o] = r;
    }
}

// ---- GEMM: 512 threads = 8 waves (2/SIMD) computing a 256x256 tile -------
// R5 post-mortem: double-barrier phasing REGRESSED (143->154.5, util 48->40)
// -> reverted to the R4 cadence (1 barrier + 1 counted vmcnt per iter, the
// 143us/48% structure). Remaining stall: the CU-shared LDS pipe is nearly
// saturated: 96 ds_read_b128 x 12cyc + 32KB DMA writes + 384 MEASURED
// conflict cyc/iter ~= 1790 cyc vs 1170 cyc MFMA. The conflicts were
// STRUCTURAL in the row-major [row][64B] layout: a 32-lane fragment read at
// 64-B row pitch touches only 16 banks per parity class (lanes l31 =
// 0,8,16,24 alias one 4-bank group; the 2-bit XOR swizzle repeats every 8
// rows and cannot fix it).
//
// Fix: CHUNK-MAJOR LDS layout, offset(r,c) = c*4096 + r*16 (r = tile row
// 0..255, c = 16-B k-chunk 0..3). Fragment reads become the canonical
// conflict-free pattern: each 32-lane half reads 512 CONTIGUOUS bytes
// (lane l31 at base + l31*16). DMA writes stay linear by remapping the
// GLOBAL side: each lane loads the 16-B chunk of its OWN row (lane = row
// within a 64-row block, chunk fixed per issue) -> LDS dest = wave-uniform
// base + lane*16 lands exactly at offset(row, c). Source permutation ==
// read layout (both-sides-or-neither). Global granule drops 64B->16B per
// lane; the 4 chunks of a row are issued same-phase by a wave pair, so
// L1/L2 merges the line (watch FETCH_SIZE as falsifier).
//
// Per K-iter (tile kt in A0/B0, kt+1 in A1/B1, kt+2 -> A2/B2), per wave:
//   1) 6 ds_read: kk=1 frags of kt -> a1/b1    (hidden under step 3)
//   2) 2 DMA: A-chunks of kt+2
//   3) 8 MFMA kk=0 (setprio)
//   4) s_waitcnt vmcnt(2) lgkmcnt(0); s_barrier
//      [kt+1's 4 DMAs drained, kt+2's A 2 stay in flight; my reads retired]
//   5) 6 ds_read: kk=0 frags of kt+1 -> a0/b0  (hidden under step 7)
//   6) 2 DMA: B-chunks of kt+2
//   7) 8 MFMA kk=1 (setprio)
//   rotate buffers.
// vmcnt ledger at step 4: outstanding = kt+1's 4 + kt+2's 2 = 6 ->
// vmcnt(2) == tile kt+1 fully landed (in-order decrement). Tail iters use
// vmcnt(0). Buffer-reuse proof: DMAs into buffer X (tile kt+2, issued iter
// kt) follow iter kt-1's step-4 lgkmcnt(0)+barrier, which retires every
// wave's last reads of X before any wave's issue. Reads of kt+1 at step 5
// follow each wave's own vmcnt drain + the same barrier. Explicit waits are
// REQUIRED: compiler alias analysis does not connect global_load_lds's LDS
// write to the ds_reads.
__global__ __launch_bounds__(512, 2) void i8gemm_bias(
        const signed char* __restrict__ x,
        const signed char* __restrict__ w,
        const int* __restrict__ bias,
        int* __restrict__ out) {
    __shared__ __align__(16) signed char la[3][256 * 64];
    __shared__ __align__(16) signed char lb[3][256 * 64];

    const int tid  = threadIdx.x;
    const int lane = tid & 63;           // 0..63
    const int wv   = tid >> 6;           // wave 0..7
    const int l31  = lane & 31;
    const int kh   = lane >> 5;          // K-half this lane supplies to MFMA
    const int wr   = wv >> 2;            // quadrant row (0..1) -> 128 rows
    const int wc   = wv & 3;             // quadrant col (0..3) -> 64 cols

    // XCD-aware bijective swizzle (512 blocks, 512%8==0): XCD k gets a
    // contiguous swz-range -> 4 A-panels x all 16 B-panels per XCD.
    const int flat = blockIdx.y * gridDim.x + blockIdx.x;   // 0..511
    const int swz  = (flat & 7) * 64 + (flat >> 3);
    const int bn0  = (swz & 15) * 256;
    const int bm0  = (swz >> 4) * 256;

    // Fused bias: C/D col = lane&31 -> bias is lane-constant per fragment.
    int bv[2];
#pragma unroll
    for (int j = 0; j < 2; ++j) bv[j] = bias[bn0 + wc * 64 + j * 32 + l31];
    v16i acc[4][2];
#pragma unroll
    for (int i = 0; i < 4; ++i)
#pragma unroll
        for (int j = 0; j < 2; ++j)
#pragma unroll
            for (int r = 0; r < 16; ++r) acc[i][j][r] = bv[j];

    // Staging (chunk-major): 16 A-issues + 16 B-issues per tile per block =
    // 4/wave. Wave wv stages row-block rb = wv>>1 (rows rb*64..+64), chunks
    // c0 = (wv&1)*2 and c0+1, for BOTH A and B. Lane l carries row rb*64+l:
    // global src = row*K + kt*64 + c*16; LDS dest = wave-uniform
    // (c*4096 + rb*1024) + l*16 = offset(rb*64+l, c). Linear write ✓.
    const int rb  = wv >> 1;
    const int c0  = (wv & 1) * 2;
    const signed char* pa = x + (long)(bm0 + rb * 64 + lane) * K_TOT + c0 * 16;
    const signed char* pb = w + (long)(bn0 + rb * 64 + lane) * K_TOT + c0 * 16;
    const int sdst = c0 * 4096 + rb * 1024;   // + u*4096 for issue u=0,1

    // Fragment reads (conflict-free): af[kk][i] at offset(wr*128+i*32+l31,
    // kk*2+kh) = (kk*2+kh)*4096 + aoff + i*512 -- contiguous 512 B per
    // 32-lane half.
    const int aoff = (wr * 128 + l31) * 16;
    const int boff = (wc * 64  + l31) * 16;
    const int ch0  = kh * 4096;          // chunk page for kk=0
    const int ch1  = (2 + kh) * 4096;    // chunk page for kk=1

    // Rotating buffer pointers: A0/B0 = tile kt, A1/B1 = kt+1, A2/B2 = kt+2.
    signed char* A0 = &la[0][0]; signed char* A1 = &la[1][0]; signed char* A2 = &la[2][0];
    signed char* B0 = &lb[0][0]; signed char* B1 = &lb[1][0]; signed char* B2 = &lb[2][0];

    // Prologue: stage tile 0 then tile 1 (grouped per tile: vmcnt decrements
    // in issue order). 4 DMAs per tile per wave (2 A-chunks + 2 B-chunks).
#pragma unroll
    for (int u = 0; u < 2; ++u) {
        gload_lds16(pa + u * 16, A0 + sdst + u * 4096);
        gload_lds16(pb + u * 16, B0 + sdst + u * 4096);
    }
#pragma unroll
    for (int u = 0; u < 2; ++u) {
        gload_lds16(pa + 64 + u * 16, A1 + sdst + u * 4096);
        gload_lds16(pb + 64 + u * 16, B1 + sdst + u * 4096);
    }
    WAIT_V4();                 // tile 0 landed (tile 1's 4 stay in flight)
    SBAR();
    SFENCE();

    // Preload kk=0 fragments of tile 0.
    v4i a0[4], b0[2], a1[4], b1[2];
#pragma unroll
    for (int i = 0; i < 4; ++i) a0[i] = *(const v4i*)(A0 + ch0 + aoff + i * 512);
#pragma unroll
    for (int j = 0; j < 2; ++j) b0[j] = *(const v4i*)(B0 + ch0 + boff + j * 512);

    const int NT = K_TOT / 64;           // 64 K-tiles
    for (int kt = 0; kt < NT; ++kt) {
        SFENCE();
        // 1) ds_read kk=1 of tile kt (consumed by step 7; hidden by step 3).
#pragma unroll
        for (int i = 0; i < 4; ++i) a1[i] = *(const v4i*)(A0 + ch1 + aoff + i * 512);
#pragma unroll
        for (int j = 0; j < 2; ++j) b1[j] = *(const v4i*)(B0 + ch1 + boff + j * 512);
        SFENCE();
        // 2) Issue A-chunk prefetch of tile kt+2 (fire-and-forget).
        if (kt + 2 < NT) {
            const long k0 = (long)(kt + 2) * 64;
#pragma unroll
            for (int u = 0; u < 2; ++u)
                gload_lds16(pa + k0 + u * 16, A2 + sdst + u * 4096);
        }
        SFENCE();
        // 3) MFMA kk=0 (8): hides step-1 reads and step-2 issues.
        __builtin_amdgcn_s_setprio(1);
#pragma unroll
        for (int i = 0; i < 4; ++i)
#pragma unroll
            for (int j = 0; j < 2; ++j)
                acc[i][j] = __builtin_amdgcn_mfma_i32_32x32x32_i8(
                    a0[i], b0[j], acc[i][j], 0, 0, 0);
        __builtin_amdgcn_s_setprio(0);
        SFENCE();
        // 4) Publish/acquire: tile kt+1 landed everywhere, my reads retired.
        if (kt + 2 < NT) { WAIT_V2_L0(); } else { WAIT_V0_L0(); }
        SFENCE();
        SBAR();
        SFENCE();
        // 5) ds_read kk=0 of tile kt+1 (hidden by step 7).
        if (kt + 1 < NT) {
#pragma unroll
            for (int i = 0; i < 4; ++i) a0[i] = *(const v4i*)(A1 + ch0 + aoff + i * 512);
#pragma unroll
            for (int j = 0; j < 2; ++j) b0[j] = *(const v4i*)(B1 + ch0 + boff + j * 512);
        }
        SFENCE();
        // 6) Issue B-chunk prefetch of tile kt+2 (fire-and-forget).
        if (kt + 2 < NT) {
            const long k0 = (long)(kt + 2) * 64;
#pragma unroll
            for (int u = 0; u < 2; ++u)
                gload_lds16(pb + k0 + u * 16, B2 + sdst + u * 4096);
        }
        SFENCE();
        // 7) MFMA kk=1 (8): hides step-5 reads (a1/b1 drained at step 4).
        __builtin_amdgcn_s_setprio(1);
#pragma unroll
        for (int i = 0; i < 4; ++i)
#pragma unroll
            for (int j = 0; j < 2; ++j)
                acc[i][j] = __builtin_amdgcn_mfma_i32_32x32x32_i8(
                    a1[i], b1[j], acc[i][j], 0, 0, 0);

        // Rotate buffers (register pointer swap, no dynamic indexing).
        signed char* t;
        t = A0; A0 = A1; A1 = A2; A2 = t;
        t = B0; B0 = B1; B1 = B2; B2 = t;
    }

    // Epilogue: C/D layout col=lane&31, row=(reg&3)+8*(reg>>2)+4*(lane>>5).
#pragma unroll
    for (int i = 0; i < 4; ++i) {
        const int mbase = bm0 + wr * 128 + i * 32 + 4 * kh;
#pragma unroll
        for (int j = 0; j < 2; ++j) {
            const int n = bn0 + wc * 64 + j * 32 + l31;
#pragma unroll
            for (int r = 0; r < 16; ++r) {
                const int m = mbase + (r & 3) + 8 * (r >> 2);
                out[(long)m * N_TOT + n] = acc[i][j][r];
            }
        }
    }
}

extern "C" void kernel_launch(void* const* d_in, const int* in_sizes, int n_in,
                              void* d_out, int out_size, void* d_ws, size_t ws_size,
                              hipStream_t stream) {
    const int* x32  = (const int*)d_in[0];  // [8192,4096] logical i8 as i32
    const int* w32  = (const int*)d_in[1];  // [4096,4096] logical i8 as i32
    const int* bias = (const int*)d_in[2];  // [4096] i32
    int*       out  = (int*)d_out;          // [8192,4096] i32

    signed char* xp = (signed char*)d_ws;
    signed char* wp = (signed char*)d_ws + (size_t)M_TOT * K_TOT;

    pack2<<<2048, 256, 0, stream>>>((const int4*)x32, (int4*)xp,
                                    (const int4*)w32, (int4*)wp);

    dim3 grid(N_TOT / 256, M_TOT / 256);  // (16, 32)
    i8gemm_bias<<<grid, 512, 0, stream>>>(xp, wp, bias, out);
}

// Round 7
// 390.512 us; speedup vs baseline: 1.0814x; 1.0814x over previous
//
#include <hip/hip_runtime.h>
#include <stdint.h>

// W8A8B32O32 Linear: y[m][n] = sum_k x[m][k]*w[n][k] + bias[n]
// M=8192, N=4096, K=4096. Inputs arrive as int32 (one int per logical int8
// element); pack to int8 in d_ws, then run the i8 MFMA GEMM.
#define M_TOT 8192
#define N_TOT 4096
#define K_TOT 4096

typedef int v4i  __attribute__((ext_vector_type(4)));
typedef int v16i __attribute__((ext_vector_type(16)));

__device__ __forceinline__ void gload_lds16(const void* g, void* l) {
    __builtin_amdgcn_global_load_lds(
        (const __attribute__((address_space(1))) unsigned int*)g,
        (__attribute__((address_space(3))) unsigned int*)l,
        16, 0, 0);
}

// gfx9 s_waitcnt simm16: vmcnt[3:0]@[3:0], expcnt@[6:4], lgkmcnt@[11:8],
// vmcnt[5:4]@[15:14].
#define WAIT_V0_L0() __builtin_amdgcn_s_waitcnt(0x0070)  // vmcnt(0) lgkmcnt(0)
#define WAIT_V0()    __builtin_amdgcn_s_waitcnt(0x0f70)  // vmcnt(0), lgkm free
#define SBAR()       __builtin_amdgcn_s_barrier()
#define SFENCE()     __builtin_amdgcn_sched_barrier(0)

// ---- fused pack int32 -> int8: 64B loads -> 16B store per thread-iter ----
// BW-bound at 240 MB (~45 us); split and fused variants measure the same ->
// already at the traffic floor.
__global__ __launch_bounds__(256) void pack2(
        const int4* __restrict__ xs, int4* __restrict__ xd,
        const int4* __restrict__ ws, int4* __restrict__ wd) {
    const int t = blockIdx.x * 256 + threadIdx.x;       // 0..524287
#pragma unroll
    for (int it = 0; it < 6; ++it) {
        const long g = (long)it * 524288 + t;
        const int4* __restrict__ src = (it < 4) ? xs : ws;
        int4* __restrict__ dst       = (it < 4) ? xd : wd;
        const long o = (it < 4) ? g : g - 2097152;
        int4 r;
        int* rp = (int*)&r;
#pragma unroll
        for (int q = 0; q < 4; ++q) {
            const int4 a = src[o * 4 + q];
            rp[q] = (a.x & 255) | ((a.y & 255) << 8) |
                    ((a.z & 255) << 16) | (a.w << 24);
        }
        dst[o] = r;
    }
}

// ---- GEMM: 512 threads = 8 waves (2/SIMD), 256x256 tile, BK=128 ----------
// R6 post-mortem: zeroing bank conflicts (chunk-major LDS) REGRESSED 143->180
// (broke global staging coalescing) -> conflicts are fully hidden; reverted
// to row-major + XOR-chunk staging. Eliminated: staging BW (R1), DMA latency
// depth (R2), barrier phasing (R5), bank conflicts (R6). Remaining ledger:
// 2681 cyc/iter/SIMD = 1171 MFMA + ~1500 per-sync overhead (barrier skew +
// waitcnt drain + issue bursts) paid once per 16 MFMAs/wave. AITER hand-asm
// runs ~32 MFMA per barrier. This version: BK=128, double-buffered
// (2 x 64 KB LDS), ONE vmcnt(0)+lgkmcnt(0) + ONE barrier per 32-MFMA iter --
// sync rate per MFMA halved, all else frozen (tile, waves, rolling f0/f1
// fragment sets keep VGPR ~100 -> 2 waves/SIMD preserved).
//
// Per K-iter (tile kt in cur=buf[kt&1], tile kt+1 -> nxt; kk = K-slice 0..3):
//   s0) 8 DMA tile kt+1 -> nxt        (issued at iter top: ~1800 cyc cover)
//   s1) 6 ds_read kk=1 -> f1
//   s2) 8 MFMA kk=0 (f0)  [covers s1]
//   s3) 6 ds_read kk=2 -> f0
//   s4) 8 MFMA kk=1 (f1)  [covers s3]
//   s5) 6 ds_read kk=3 -> f1
//   s6) 8 MFMA kk=2 (f0)  [covers s5]
//   s7) s_waitcnt vmcnt(0) lgkmcnt(0); s_barrier
//       [tile kt+1 landed everywhere; all my reads of cur retired]
//   s8) 6 ds_read kk=0 of tile kt+1 (nxt) -> f0
//   s9) 8 MFMA kk=3 (f1)  [covers s8]
//   swap cur/nxt.
// Buffer-reuse proof: s0 of iter kt writes nxt = buf[(kt+1)&1], which held
// tile kt-1, last read at iter kt-1 (s1..s5); iter kt-1's s7 lgkmcnt(0)
// retires those reads in EVERY wave before its barrier, and s0 is after.
// s8's reads of tile kt+1 follow this iter's s7 vmcnt(0) drain + barrier.
// Explicit waits are REQUIRED: compiler alias analysis does not connect
// global_load_lds's LDS write to the ds_reads.
// Staging (row-major, 128-B rows, 3-bit XOR chunk swizzle): stored_chunk =
// logical_chunk ^ (row&7). Issue u covers rows u*8+(lane>>3); stored chunk
// = lane&7 -> fetch chunk fc = (lane&7)^((lane>>3)&7); 8 lanes/row read 128
// contiguous B (coalesced), LDS dest = uniform base + lane*16 (linear).
// Fragment reads: row = base + l31 (bases = 0 mod 8) -> swr = l31&7; logical
// chunk kk*2+kh at slot (kk*2+kh)^swr. Residual 4-way conflicts are hidden
// (R6 measured: zero-conflict layout gained nothing).
__global__ __launch_bounds__(512, 2) void i8gemm_bias(
        const signed char* __restrict__ x,
        const signed char* __restrict__ w,
        const int* __restrict__ bias,
        int* __restrict__ out) {
    __shared__ __align__(16) signed char la[2][256 * 128];
    __shared__ __align__(16) signed char lb[2][256 * 128];

    const int tid  = threadIdx.x;
    const int lane = tid & 63;           // 0..63
    const int wv   = tid >> 6;           // wave 0..7
    const int l31  = lane & 31;
    const int kh   = lane >> 5;          // K-half this lane supplies to MFMA
    const int wr   = wv >> 2;            // quadrant row (0..1) -> 128 rows
    const int wc   = wv & 3;             // quadrant col (0..3) -> 64 cols

    // XCD-aware bijective swizzle (512 blocks, 512%8==0): XCD k gets a
    // contiguous swz-range -> 4 A-panels x all 16 B-panels per XCD.
    const int flat = blockIdx.y * gridDim.x + blockIdx.x;   // 0..511
    const int swz  = (flat & 7) * 64 + (flat >> 3);
    const int bn0  = (swz & 15) * 256;
    const int bm0  = (swz >> 4) * 256;

    // Fused bias: C/D col = lane&31 -> bias is lane-constant per fragment.
    int bv[2];
#pragma unroll
    for (int j = 0; j < 2; ++j) bv[j] = bias[bn0 + wc * 64 + j * 32 + l31];
    v16i acc[4][2];
#pragma unroll
    for (int i = 0; i < 4; ++i)
#pragma unroll
        for (int j = 0; j < 2; ++j)
#pragma unroll
            for (int r = 0; r < 16; ++r) acc[i][j][r] = bv[j];

    // Staging: wave wv covers rows [wv*32, wv*32+32) of A and B tiles:
    // 4 issues x (8 rows x 8 chunks) each, for each matrix.
    const int fc = (lane & 7) ^ ((lane >> 3) & 7);
    const signed char* pa = x + (long)(bm0 + wv * 32 + (lane >> 3)) * K_TOT + fc * 16;
    const signed char* pb = w + (long)(bn0 + wv * 32 + (lane >> 3)) * K_TOT + fc * 16;
    const int sdst = wv * 32 * 128;      // + u*1024 per issue u

    // Fragment reads: A row = wr*128 + i*32 + l31, B row = wc*64 + j*32 + l31.
    const int swr  = l31 & 7;
    const int aoff = (wr * 128 + l31) * 128;
    const int boff = (wc * 64  + l31) * 128;
    // chunk byte offset for K-slice kk: ((kk*2+kh) ^ swr) * 16
    const int cs0 = ((0 + kh) ^ swr) * 16;
    const int cs1 = ((2 + kh) ^ swr) * 16;
    const int cs2 = ((4 + kh) ^ swr) * 16;
    const int cs3 = ((6 + kh) ^ swr) * 16;

    // Double buffer pointers.
    signed char* A0 = &la[0][0]; signed char* A1 = &la[1][0];
    signed char* B0 = &lb[0][0]; signed char* B1 = &lb[1][0];

    // Prologue: stage tile 0 -> buf0 (8 DMAs/wave).
#pragma unroll
    for (int u = 0; u < 4; ++u) {
        gload_lds16(pa + (long)u * 8 * K_TOT, A0 + sdst + u * 1024);
        gload_lds16(pb + (long)u * 8 * K_TOT, B0 + sdst + u * 1024);
    }
    WAIT_V0();
    SBAR();
    SFENCE();

    // Preload kk=0 fragments of tile 0 -> f0.
    v4i a0[4], b0[2], a1[4], b1[2];
#pragma unroll
    for (int i = 0; i < 4; ++i) a0[i] = *(const v4i*)(A0 + aoff + i * 4096 + cs0);
#pragma unroll
    for (int j = 0; j < 2; ++j) b0[j] = *(const v4i*)(B0 + boff + j * 4096 + cs0);

    const int NT = K_TOT / 128;          // 32 K-tiles
    for (int kt = 0; kt < NT; ++kt) {
        SFENCE();
        // s0) Issue tile kt+1's 8 DMAs (fire-and-forget, ~1800 cyc cover).
        if (kt + 1 < NT) {
            const long k0 = (long)(kt + 1) * 128;
#pragma unroll
            for (int u = 0; u < 4; ++u) {
                gload_lds16(pa + k0 + (long)u * 8 * K_TOT, A1 + sdst + u * 1024);
                gload_lds16(pb + k0 + (long)u * 8 * K_TOT, B1 + sdst + u * 1024);
            }
        }
        SFENCE();
        // s1) reads kk=1 -> f1.
#pragma unroll
        for (int i = 0; i < 4; ++i) a1[i] = *(const v4i*)(A0 + aoff + i * 4096 + cs1);
#pragma unroll
        for (int j = 0; j < 2; ++j) b1[j] = *(const v4i*)(B0 + boff + j * 4096 + cs1);
        SFENCE();
        // s2) MFMA kk=0 (f0).
        __builtin_amdgcn_s_setprio(1);
#pragma unroll
        for (int i = 0; i < 4; ++i)
#pragma unroll
            for (int j = 0; j < 2; ++j)
                acc[i][j] = __builtin_amdgcn_mfma_i32_32x32x32_i8(
                    a0[i], b0[j], acc[i][j], 0, 0, 0);
        __builtin_amdgcn_s_setprio(0);
        SFENCE();
        // s3) reads kk=2 -> f0.
#pragma unroll
        for (int i = 0; i < 4; ++i) a0[i] = *(const v4i*)(A0 + aoff + i * 4096 + cs2);
#pragma unroll
        for (int j = 0; j < 2; ++j) b0[j] = *(const v4i*)(B0 + boff + j * 4096 + cs2);
        SFENCE();
        // s4) MFMA kk=1 (f1).
        __builtin_amdgcn_s_setprio(1);
#pragma unroll
        for (int i = 0; i < 4; ++i)
#pragma unroll
            for (int j = 0; j < 2; ++j)
                acc[i][j] = __builtin_amdgcn_mfma_i32_32x32x32_i8(
                    a1[i], b1[j], acc[i][j], 0, 0, 0);
        __builtin_amdgcn_s_setprio(0);
        SFENCE();
        // s5) reads kk=3 -> f1.
#pragma unroll
        for (int i = 0; i < 4; ++i) a1[i] = *(const v4i*)(A0 + aoff + i * 4096 + cs3);
#pragma unroll
        for (int j = 0; j < 2; ++j) b1[j] = *(const v4i*)(B0 + boff + j * 4096 + cs3);
        SFENCE();
        // s6) MFMA kk=2 (f0).
        __builtin_amdgcn_s_setprio(1);
#pragma unroll
        for (int i = 0; i < 4; ++i)
#pragma unroll
            for (int j = 0; j < 2; ++j)
                acc[i][j] = __builtin_amdgcn_mfma_i32_32x32x32_i8(
                    a0[i], b0[j], acc[i][j], 0, 0, 0);
        __builtin_amdgcn_s_setprio(0);
        SFENCE();
        // s7) THE sync point: tile kt+1 landed; all reads of cur retired.
        WAIT_V0_L0();
        SFENCE();
        SBAR();
        SFENCE();
        // s8) reads kk=0 of tile kt+1 (nxt) -> f0 (covered by s9).
        if (kt + 1 < NT) {
#pragma unroll
            for (int i = 0; i < 4; ++i) a0[i] = *(const v4i*)(A1 + aoff + i * 4096 + cs0);
#pragma unroll
            for (int j = 0; j < 2; ++j) b0[j] = *(const v4i*)(B1 + boff + j * 4096 + cs0);
        }
        SFENCE();
        // s9) MFMA kk=3 (f1).
        __builtin_amdgcn_s_setprio(1);
#pragma unroll
        for (int i = 0; i < 4; ++i)
#pragma unroll
            for (int j = 0; j < 2; ++j)
                acc[i][j] = __builtin_amdgcn_mfma_i32_32x32x32_i8(
                    a1[i], b1[j], acc[i][j], 0, 0, 0);
        __builtin_amdgcn_s_setprio(0);

        // Swap double buffers (register pointer swap, no dynamic indexing).
        signed char* t;
        t = A0; A0 = A1; A1 = t;
        t = B0; B0 = B1; B1 = t;
    }

    // Epilogue: C/D layout col=lane&31, row=(reg&3)+8*(reg>>2)+4*(lane>>5).
#pragma unroll
    for (int i = 0; i < 4; ++i) {
        const int mbase = bm0 + wr * 128 + i * 32 + 4 * kh;
#pragma unroll
        for (int j = 0; j < 2; ++j) {
            const int n = bn0 + wc * 64 + j * 32 + l31;
#pragma unroll
            for (int r = 0; r < 16; ++r) {
                const int m = mbase + (r & 3) + 8 * (r >> 2);
                out[(long)m * N_TOT + n] = acc[i][j][r];
            }
        }
    }
}

extern "C" void kernel_launch(void* const* d_in, const int* in_sizes, int n_in,
                              void* d_out, int out_size, void* d_ws, size_t ws_size,
                              hipStream_t stream) {
    const int* x32  = (const int*)d_in[0];  // [8192,4096] logical i8 as i32
    const int* w32  = (const int*)d_in[1];  // [4096,4096] logical i8 as i32
    const int* bias = (const int*)d_in[2];  // [4096] i32
    int*       out  = (int*)d_out;          // [8192,4096] i32

    signed char* xp = (signed char*)d_ws;
    signed char* wp = (signed char*)d_ws + (size_t)M_TOT * K_TOT;

    pack2<<<2048, 256, 0, stream>>>((const int4*)x32, (int4*)xp,
                                    (const int4*)w32, (int4*)wp);

    dim3 grid(N_TOT / 256, M_TOT / 256);  // (16, 32)
    i8gemm_bias<<<grid, 512, 0, stream>>>(xp, wp, bias, out);
}